// Round 7
// baseline (403.195 us; speedup 1.0000x reference)
//
#include <hip/hip_runtime.h>

// TGCNCell forward:
//   h_agg = segment_sum(x[src], dst);  gates = h_agg @ W_ih.T + b_ih + b_hh
//   c = sigm(i)*tanh(g); h = sigm(o)*tanh(c); out = relu(h)
// f-gate rows (32:64) and W_hh are numerically unused.
//
// R6 resubmit (previous bench never ran): two-level counting sort
// (50 superbins -> 1000 bins) so every global scatter write is a long
// contiguous run, then per-bin LDS accumulation with 8-deep batched x-row
// loads (latency hiding; R5's p2 was latency-bound at 294us with 1 edge in
// flight per group).

constexpr int NN   = 100000;
constexpr int NE   = 1600000;
constexpr int F    = 32;
// level 1: superbins
constexpr int NSB  = 50;            // superbins
constexpr int NPSB = 2000;          // nodes per superbin (dl2 fits 11 bits)
constexpr int CAP1 = 34816;         // = 17*2048; Poisson(32000)+15.7sigma
constexpr int EPA  = 3200;          // edges per pA block
constexpr int NBA  = NE / EPA;      // 500 blocks
// level 2: bins
constexpr int NPB  = 100;           // nodes per bin (dl fits 8 bits)
constexpr int NBIN = NN / NPB;      // 1000
constexpr int BPSB = NPSB / NPB;    // 20 bins per superbin
constexpr int CHUNK = 2048;
constexpr int NCH  = CAP1 / CHUNK;  // 17 chunks per superbin
constexpr int CAP2 = 1920;          // Poisson(1600)+8sigma
static_assert(NSB * NPSB == NN, "superbin geometry");
static_assert(NBIN * NPB == NN, "bin geometry");
static_assert(NBA * EPA == NE, "edge partition");
static_assert(NCH * CHUNK == CAP1, "chunking");

// ---------------------------------------------------------------------------
// pA: sort edges into 50 superbins. Packed value = (src<<11) | dstLocal2000.
// Per block: LDS hist -> serial scan(50) -> global reserve -> LDS-staged
// scatter -> writeout (avg run = 3200/50 = 64 edges = 256B contiguous).
// ---------------------------------------------------------------------------
__global__ __launch_bounds__(256) void pA(
    const int* __restrict__ src, const int* __restrict__ dst,
    unsigned int* __restrict__ seg1, int* __restrict__ fill1)
{
    __shared__ int hist[NSB], sbase[NSB], cur[NSB], adj[NSB];
    __shared__ unsigned int stg[EPA];   // 12.8KB
    __shared__ int gpos[EPA];           // 12.8KB

    const int t  = threadIdx.x;
    const int e0 = blockIdx.x * EPA;

    for (int i = t; i < NSB; i += 256) hist[i] = 0;
    __syncthreads();

    for (int e = e0 + t; e < e0 + EPA; e += 256)
        atomicAdd(&hist[(unsigned)dst[e] / NPSB], 1);
    __syncthreads();

    if (t == 0) { int acc = 0; for (int b = 0; b < NSB; ++b) { sbase[b] = acc; acc += hist[b]; } }
    __syncthreads();

    for (int b = t; b < NSB; b += 256) {
        int c  = hist[b];
        int gb = c ? atomicAdd(&fill1[b], c) : 0;
        adj[b] = gb - sbase[b];         // slot-in-segment = adj + local_pos
        cur[b] = sbase[b];
    }
    __syncthreads();

    for (int e = e0 + t; e < e0 + EPA; e += 256) {
        unsigned d = (unsigned)dst[e], s = (unsigned)src[e];
        unsigned sb  = d / NPSB;
        unsigned dl2 = d - sb * NPSB;
        int lp   = atomicAdd(&cur[sb], 1);
        int slot = adj[sb] + lp;
        stg[lp]  = (s << 11) | dl2;
        gpos[lp] = (slot < CAP1) ? (int)(sb * CAP1 + slot) : -1;  // overflow guard
    }
    __syncthreads();

    for (int p = t; p < EPA; p += 256) { int g = gpos[p]; if (g >= 0) seg1[g] = stg[p]; }
}

// ---------------------------------------------------------------------------
// pB: refine one 2048-edge chunk of a superbin into its 20 bins.
// Packed value -> (src<<8) | dstLocal100. Run length ~100 edges.
// ---------------------------------------------------------------------------
__global__ __launch_bounds__(256) void pB(
    const unsigned int* __restrict__ seg1, const int* __restrict__ fill1,
    unsigned int* __restrict__ seg2, int* __restrict__ fill2)
{
    __shared__ int hist[BPSB], sbase[BPSB], cur[BPSB], adj[BPSB];
    __shared__ unsigned int stg[CHUNK]; // 8KB
    __shared__ int gpos[CHUNK];         // 8KB

    const int t  = threadIdx.x;
    const int sb = blockIdx.x / NCH;
    const int ch = blockIdx.x % NCH;

    int n1 = fill1[sb]; if (n1 > CAP1) n1 = CAP1;
    int cnt = n1 - ch * CHUNK;
    if (cnt <= 0) return;               // uniform across block (before barriers)
    if (cnt > CHUNK) cnt = CHUNK;
    const unsigned int* sg = seg1 + (size_t)sb * CAP1 + ch * CHUNK;

    if (t < BPSB) hist[t] = 0;
    __syncthreads();

    for (int i = t; i < cnt; i += 256) atomicAdd(&hist[(sg[i] & 2047u) / NPB], 1);
    __syncthreads();

    if (t == 0) { int acc = 0; for (int b = 0; b < BPSB; ++b) { sbase[b] = acc; acc += hist[b]; } }
    __syncthreads();

    if (t < BPSB) {
        int c  = hist[t];
        int gb = c ? atomicAdd(&fill2[sb * BPSB + t], c) : 0;
        adj[t] = gb - sbase[t];
        cur[t] = sbase[t];
    }
    __syncthreads();

    for (int i = t; i < cnt; i += 256) {
        unsigned v = sg[i];
        unsigned s = v >> 11, dl2 = v & 2047u;
        unsigned lb = dl2 / NPB, dl = dl2 - lb * NPB;
        int lp   = atomicAdd(&cur[lb], 1);
        int slot = adj[lb] + lp;
        stg[lp]  = (s << 8) | dl;
        gpos[lp] = (slot < CAP2) ? (int)((size_t)(sb * BPSB + lb) * CAP2 + slot) : -1;
    }
    __syncthreads();

    for (int p = t; p < cnt; p += 256) { int g = gpos[p]; if (g >= 0) seg2[g] = stg[p]; }
}

// ---------------------------------------------------------------------------
// p2: one block per bin (1000 blocks, 512 thr). Stage the bin's edge list in
// LDS; gather with 8-deep batched x loads (16 groups x 8 edges per iter);
// accumulate h_agg in LDS (ds_add_f32); fused gates + activations.
// ---------------------------------------------------------------------------
__device__ __forceinline__ float sigm(float v)  { return 1.0f / (1.0f + __expf(-v)); }
__device__ __forceinline__ float tanh_(float v) { return 1.0f - 2.0f / (__expf(2.0f * v) + 1.0f); }

__global__ __launch_bounds__(512) void p2(
    const float* __restrict__ x,
    const unsigned int* __restrict__ seg2, const int* __restrict__ fill2,
    const float* __restrict__ W,        // (128,32) row-major
    const float* __restrict__ b_ih, const float* __restrict__ b_hh,
    float* __restrict__ out)
{
    __shared__ float hs[NPB * F];       // 12.8KB
    __shared__ float Ws[96 * 33];       // 12.7KB, stride 33 conflict-free
    __shared__ float bs[96];
    __shared__ unsigned int sg[CAP2];   // 7.7KB

    const int t   = threadIdx.x;
    const int bin = blockIdx.x;

    int nE = fill2[bin]; if (nE > CAP2) nE = CAP2;

    for (int i = t; i < 96 * 32; i += 512) {
        int r = i >> 5, k = i & 31;
        int sr = (r < 32) ? r : r + 32;           // skip f rows 32..63
        Ws[r * 33 + k] = W[sr * 32 + k];
    }
    if (t < 96) { int sr = (t < 32) ? t : t + 32; bs[t] = b_ih[sr] + b_hh[sr]; }
    for (int i = t; i < NPB * F; i += 512) hs[i] = 0.0f;
    const unsigned int* s2 = seg2 + (size_t)bin * CAP2;
    for (int i = t; i < nE; i += 512) sg[i] = s2[i];
    __syncthreads();

    // gather: 16 groups of 32 lanes, 8 edges per group per iteration
    const int lane = t & 31, g = t >> 5;
    for (int base = 0; base < nE; base += 128) {
        int e8  = base + g * 8;
        int ecl = e8 + (lane & 7); if (ecl > nE - 1) ecl = nE - 1;
        unsigned sv = sg[ecl];              // octet-coalesced LDS read
        float xv[8]; int dlv[8];
        #pragma unroll
        for (int k = 0; k < 8; ++k) {       // issue 8 independent x-row loads
            unsigned v = __shfl(sv, k, 8);  // broadcast within octet
            int s  = (int)(v >> 8);
            dlv[k] = (int)(v & 255u);
            xv[k]  = x[s * F + lane];       // clamped dups harmless (skipped below)
        }
        #pragma unroll
        for (int k = 0; k < 8; ++k) {
            if (e8 + k < nE) atomicAdd(&hs[dlv[k] * F + lane], xv[k]);  // ds_add_f32
        }
    }
    __syncthreads();

    // gates: thread -> (node, col j)
    for (int i = t; i < NPB * F; i += 512) {
        int node = i >> 5, j = i & 31;
        const float* h  = &hs[node * F];
        const float* wi = &Ws[j * 33];
        const float* wg = &Ws[(32 + j) * 33];
        const float* wo = &Ws[(64 + j) * 33];
        float ai = bs[j], ag = bs[32 + j], ao = bs[64 + j];
        #pragma unroll
        for (int k = 0; k < F; ++k) {
            float hv = h[k];
            ai += hv * wi[k];
            ag += hv * wg[k];
            ao += hv * wo[k];
        }
        float c  = sigm(ai) * tanh_(ag);
        float hh = sigm(ao) * tanh_(c);
        out[(bin * NPB + node) * F + j] = fmaxf(hh, 0.0f);
    }
}

// ---------------------------------------------------------------------------
extern "C" void kernel_launch(void* const* d_in, const int* in_sizes, int n_in,
                              void* d_out, int out_size, void* d_ws, size_t ws_size,
                              hipStream_t stream) {
    const float* x    = (const float*)d_in[0];
    const int*   src  = (const int*)  d_in[1];
    const int*   dst  = (const int*)  d_in[2];
    const float* W_ih = (const float*)d_in[3];
    // d_in[4] = W_hh : numerically unused
    const float* b_ih = (const float*)d_in[5];
    const float* b_hh = (const float*)d_in[6];
    float* out = (float*)d_out;

    // ws layout: seg1 (6.96MB) | seg2 (7.68MB) | fill1 (64 ints) | fill2 (1000 ints)
    unsigned int* seg1 = (unsigned int*)d_ws;
    unsigned int* seg2 = seg1 + (size_t)NSB * CAP1;
    int* fill1 = (int*)(seg2 + (size_t)NBIN * CAP2);
    int* fill2 = fill1 + 64;

    hipMemsetAsync(fill1, 0, (64 + NBIN) * sizeof(int), stream);
    pA<<<NBA,        256, 0, stream>>>(src, dst, seg1, fill1);
    pB<<<NSB * NCH,  256, 0, stream>>>(seg1, fill1, seg2, fill2);
    p2<<<NBIN,       512, 0, stream>>>(x, seg2, fill2, W_ih, b_ih, b_hh, out);
}

// Round 8
// 153.742 us; speedup vs baseline: 2.6226x; 2.6226x over previous
//
#include <hip/hip_runtime.h>

// TGCNCell forward:
//   h_agg = segment_sum(x[src], dst);  gates = h_agg @ W_ih.T + b_ih + b_hh
//   c = sigm(i)*tanh(g); h = sigm(o)*tanh(c); out = relu(h)
// f-gate rows (32:64) and W_hh are numerically unused.
//
// R8: R5/R6's p2 both hit ~300us regardless of structure => shared wall =
// 51.2M ds_add_f32 lane-atomics (~0.28/cyc/CU measured). Eliminate them:
// in-LDS counting sort by node (1 atomic per EDGE via rank trick), then
// register accumulation per group-owned node (no atomics in the hot path).
// pA/pB also use the rank trick (1 atomic/edge instead of 2).

constexpr int NN   = 100000;
constexpr int NE   = 1600000;
constexpr int F    = 32;
// level 1: superbins
constexpr int NSB  = 50;            // superbins
constexpr int NPSB = 2000;          // nodes per superbin (dl2 fits 11 bits)
constexpr int CAP1 = 34816;         // = 17*2048; Poisson(32000)+15.7sigma
constexpr int EPA  = 3200;          // edges per pA block
constexpr int NBA  = NE / EPA;      // 500 blocks
// level 2: bins
constexpr int NPB  = 100;           // nodes per bin (dl fits 8 bits)
constexpr int NBIN = NN / NPB;      // 1000
constexpr int BPSB = NPSB / NPB;    // 20 bins per superbin
constexpr int CHUNK = 2048;
constexpr int NCH  = CAP1 / CHUNK;  // 17 chunks per superbin
constexpr int CAP2 = 1920;          // Poisson(1600)+8sigma
static_assert(NSB * NPSB == NN, "superbin geometry");
static_assert(NBIN * NPB == NN, "bin geometry");
static_assert(NBA * EPA == NE, "edge partition");
static_assert(NCH * CHUNK == CAP1, "chunking");

// ---------------------------------------------------------------------------
// pA: sort edges into 50 superbins. rank trick: the histogram atomic RETURNS
// each edge's block-local rank, so the scatter pass needs no cursor atomic.
// ---------------------------------------------------------------------------
__global__ __launch_bounds__(256) void pA(
    const int* __restrict__ src, const int* __restrict__ dst,
    unsigned int* __restrict__ seg1, int* __restrict__ fill1)
{
    __shared__ int hist[NSB], sbase[NSB], gbase[NSB];
    __shared__ unsigned int stg[EPA];   // 12.8KB
    __shared__ int gpos[EPA];           // 12.8KB

    const int t  = threadIdx.x;
    const int e0 = blockIdx.x * EPA;

    for (int i = t; i < NSB; i += 256) hist[i] = 0;
    __syncthreads();

    int rS[13], rD[13], rR[13];         // EPA/256 = 12.5 -> up to 13 per thread
    #pragma unroll
    for (int j = 0; j < 13; ++j) {
        int e = e0 + t + j * 256;
        if (e < e0 + EPA) {
            int d = dst[e];
            rS[j] = src[e];
            rD[j] = d;
            rR[j] = atomicAdd(&hist[(unsigned)d / NPSB], 1);  // rank in block-bin
        }
    }
    __syncthreads();

    if (t == 0) { int acc = 0; for (int b = 0; b < NSB; ++b) { sbase[b] = acc; acc += hist[b]; } }
    __syncthreads();

    if (t < NSB) { int c = hist[t]; gbase[t] = c ? atomicAdd(&fill1[t], c) : 0; }
    __syncthreads();

    #pragma unroll
    for (int j = 0; j < 13; ++j) {
        int e = e0 + t + j * 256;
        if (e < e0 + EPA) {
            unsigned d = (unsigned)rD[j];
            unsigned sb = d / NPSB, dl2 = d - sb * NPSB;
            int lp   = sbase[sb] + rR[j];          // block-local sorted pos
            int slot = gbase[sb] + rR[j];          // pos in global segment
            stg[lp]  = ((unsigned)rS[j] << 11) | dl2;
            gpos[lp] = (slot < CAP1) ? (int)(sb * CAP1 + slot) : -1;
        }
    }
    __syncthreads();

    for (int p = t; p < EPA; p += 256) { int g = gpos[p]; if (g >= 0) seg1[g] = stg[p]; }
}

// ---------------------------------------------------------------------------
// pB: refine one 2048-edge chunk of a superbin into its 20 bins (rank trick).
// ---------------------------------------------------------------------------
__global__ __launch_bounds__(256) void pB(
    const unsigned int* __restrict__ seg1, const int* __restrict__ fill1,
    unsigned int* __restrict__ seg2, int* __restrict__ fill2)
{
    __shared__ int hist[BPSB], sbase[BPSB], gbase[BPSB];
    __shared__ unsigned int stg[CHUNK]; // 8KB
    __shared__ int gpos[CHUNK];         // 8KB

    const int t  = threadIdx.x;
    const int sb = blockIdx.x / NCH;
    const int ch = blockIdx.x % NCH;

    int n1 = fill1[sb]; if (n1 > CAP1) n1 = CAP1;
    int cnt = n1 - ch * CHUNK;
    if (cnt <= 0) return;               // uniform across block (before barriers)
    if (cnt > CHUNK) cnt = CHUNK;
    const unsigned int* sg = seg1 + (size_t)sb * CAP1 + ch * CHUNK;

    if (t < BPSB) hist[t] = 0;
    __syncthreads();

    unsigned rV[8]; int rR[8];          // CHUNK/256 = 8
    #pragma unroll
    for (int j = 0; j < 8; ++j) {
        int i = t + j * 256;
        if (i < cnt) {
            unsigned v = sg[i];
            rV[j] = v;
            rR[j] = atomicAdd(&hist[(v & 2047u) / NPB], 1);
        }
    }
    __syncthreads();

    if (t == 0) { int acc = 0; for (int b = 0; b < BPSB; ++b) { sbase[b] = acc; acc += hist[b]; } }
    __syncthreads();

    if (t < BPSB) { int c = hist[t]; gbase[t] = c ? atomicAdd(&fill2[sb * BPSB + t], c) : 0; }
    __syncthreads();

    #pragma unroll
    for (int j = 0; j < 8; ++j) {
        int i = t + j * 256;
        if (i < cnt) {
            unsigned v = rV[j];
            unsigned s = v >> 11, dl2 = v & 2047u;
            unsigned lb = dl2 / NPB, dl = dl2 - lb * NPB;
            int lp   = sbase[lb] + rR[j];
            int slot = gbase[lb] + rR[j];
            stg[lp]  = (s << 8) | dl;
            gpos[lp] = (slot < CAP2) ? (int)((size_t)(sb * BPSB + lb) * CAP2 + slot) : -1;
        }
    }
    __syncthreads();

    for (int p = t; p < cnt; p += 256) { int g = gpos[p]; if (g >= 0) seg2[g] = stg[p]; }
}

// ---------------------------------------------------------------------------
// p2: one block per bin. In-LDS counting sort by node (1 atomic/edge), then
// each 32-lane group (lane = feature) owns nodes dl = g, g+16, ... and
// accumulates h in a REGISTER over that node's contiguous edge range
// (8-deep batched broadcast reads + x-row loads, plain v_add_f32).
// Zero atomics in the per-edge-per-feature path. Fused gates + activations.
// ---------------------------------------------------------------------------
__device__ __forceinline__ float sigm(float v)  { return 1.0f / (1.0f + __expf(-v)); }
__device__ __forceinline__ float tanh_(float v) { return 1.0f - 2.0f / (__expf(2.0f * v) + 1.0f); }

__global__ __launch_bounds__(512) void p2(
    const float* __restrict__ x,
    const unsigned int* __restrict__ seg2, const int* __restrict__ fill2,
    const float* __restrict__ W,        // (128,32) row-major
    const float* __restrict__ b_ih, const float* __restrict__ b_hh,
    float* __restrict__ out)
{
    __shared__ float hs[NPB * F];       // 12.8KB
    __shared__ float Ws[96 * 33];       // 12.7KB, stride 33 conflict-free
    __shared__ float bs[96];
    __shared__ unsigned int sgl[CAP2];  // 7.7KB node-sorted edge list
    __shared__ int cnt[NPB], start[NPB];

    const int t   = threadIdx.x;
    const int bin = blockIdx.x;

    for (int i = t; i < 96 * 32; i += 512) {
        int r = i >> 5, k = i & 31;
        int sr = (r < 32) ? r : r + 32;           // skip f rows 32..63
        Ws[r * 33 + k] = W[sr * 32 + k];
    }
    if (t < 96) { int sr = (t < 32) ? t : t + 32; bs[t] = b_ih[sr] + b_hh[sr]; }
    if (t < NPB) cnt[t] = 0;
    __syncthreads();

    int nE = fill2[bin]; if (nE > CAP2) nE = CAP2;
    const unsigned int* s2 = seg2 + (size_t)bin * CAP2;

    unsigned rV[4]; int rR[4];          // CAP2/512 = 3.75 -> 4
    #pragma unroll
    for (int j = 0; j < 4; ++j) {
        int i = t + j * 512;
        if (i < nE) { unsigned v = s2[i]; rV[j] = v; rR[j] = atomicAdd(&cnt[v & 255u], 1); }
    }
    __syncthreads();

    if (t == 0) { int acc = 0; for (int b = 0; b < NPB; ++b) { start[b] = acc; acc += cnt[b]; } }
    __syncthreads();

    #pragma unroll
    for (int j = 0; j < 4; ++j) {
        int i = t + j * 512;
        if (i < nE) { unsigned v = rV[j]; sgl[start[v & 255u] + rR[j]] = v; }
    }
    __syncthreads();

    // gather: group g owns nodes dl = g + 16*m; register accumulate
    const int lane = t & 31, g = t >> 5;
    for (int dl = g; dl < NPB; dl += 16) {
        int st = start[dl], cn = cnt[dl];
        float acc = 0.0f;
        for (int b = 0; b < cn; b += 8) {
            float xv[8];
            #pragma unroll
            for (int k = 0; k < 8; ++k) {         // 8 independent x-row loads
                int idx = b + k; if (idx > cn - 1) idx = cn - 1;  // clamp (dups masked below)
                unsigned v = sgl[st + idx];        // broadcast LDS read (uniform in group)
                xv[k] = x[(v >> 8) * F + lane];
            }
            #pragma unroll
            for (int k = 0; k < 8; ++k) acc += (b + k < cn) ? xv[k] : 0.0f;
        }
        hs[dl * F + lane] = acc;                   // plain ds_write, once per node
    }
    __syncthreads();

    // gates: thread -> (node, col j)
    for (int i = t; i < NPB * F; i += 512) {
        int node = i >> 5, j = i & 31;
        const float* h  = &hs[node * F];
        const float* wi = &Ws[j * 33];
        const float* wg = &Ws[(32 + j) * 33];
        const float* wo = &Ws[(64 + j) * 33];
        float ai = bs[j], ag = bs[32 + j], ao = bs[64 + j];
        #pragma unroll
        for (int k = 0; k < F; ++k) {
            float hv = h[k];
            ai += hv * wi[k];
            ag += hv * wg[k];
            ao += hv * wo[k];
        }
        float c  = sigm(ai) * tanh_(ag);
        float hh = sigm(ao) * tanh_(c);
        out[(bin * NPB + node) * F + j] = fmaxf(hh, 0.0f);
    }
}

// ---------------------------------------------------------------------------
extern "C" void kernel_launch(void* const* d_in, const int* in_sizes, int n_in,
                              void* d_out, int out_size, void* d_ws, size_t ws_size,
                              hipStream_t stream) {
    const float* x    = (const float*)d_in[0];
    const int*   src  = (const int*)  d_in[1];
    const int*   dst  = (const int*)  d_in[2];
    const float* W_ih = (const float*)d_in[3];
    // d_in[4] = W_hh : numerically unused
    const float* b_ih = (const float*)d_in[5];
    const float* b_hh = (const float*)d_in[6];
    float* out = (float*)d_out;

    // ws layout: seg1 (6.96MB) | seg2 (7.68MB) | fill1 (64 ints) | fill2 (1000 ints)
    unsigned int* seg1 = (unsigned int*)d_ws;
    unsigned int* seg2 = seg1 + (size_t)NSB * CAP1;
    int* fill1 = (int*)(seg2 + (size_t)NBIN * CAP2);
    int* fill2 = fill1 + 64;

    hipMemsetAsync(fill1, 0, (64 + NBIN) * sizeof(int), stream);
    pA<<<NBA,       256, 0, stream>>>(src, dst, seg1, fill1);
    pB<<<NSB * NCH, 256, 0, stream>>>(seg1, fill1, seg2, fill2);
    p2<<<NBIN,      512, 0, stream>>>(x, seg2, fill2, W_ih, b_ih, b_hh, out);
}